// Round 2
// baseline (398.887 us; speedup 1.0000x reference)
//
#include <hip/hip_runtime.h>

// Problem constants (from reference setup_inputs): B=4, S=8192, D=1024, fp32.
constexpr int B  = 4;
constexpr int S  = 8192;
constexpr int D  = 1024;
constexpr int D4 = D / 4;      // 256 float4 per (b, s) row — one 256-thread block

// ---------------- Phase 1: per-chunk aggregates ----------------
// Block (c, b): scan chunk c of batch b with h_in = 0. Thread t owns 4 channels
// (one float4). Writes X (combine result) and A (prod of alpha) aggregates,
// layout [b][c][d] so phase1 writes and phase3 prefix reads stay coalesced.
template <int C>
__global__ __launch_bounds__(256) void phase1_k(const float4* __restrict__ x,
                                                const float4* __restrict__ a,
                                                float4* __restrict__ Xagg,
                                                float4* __restrict__ Aagg) {
    constexpr int L = S / C;
    const int t = threadIdx.x;
    const int c = blockIdx.x;
    const int b = blockIdx.y;
    size_t base = ((size_t)(b * S + c * L)) * D4 + t;

    float4 X = {0.f, 0.f, 0.f, 0.f};
    float4 A = {1.f, 1.f, 1.f, 1.f};
    #pragma unroll 4
    for (int s = 0; s < L; ++s) {
        float4 xv = x[base + (size_t)s * D4];
        float4 av = a[base + (size_t)s * D4];
        X.x = fmaf(av.x, X.x, xv.x);
        X.y = fmaf(av.y, X.y, xv.y);
        X.z = fmaf(av.z, X.z, xv.z);
        X.w = fmaf(av.w, X.w, xv.w);
        A.x *= av.x; A.y *= av.y; A.z *= av.z; A.w *= av.w;
    }
    size_t o = ((size_t)(b * C + c)) * D4 + t;
    Xagg[o] = X;
    Aagg[o] = A;
}

// ---------------- Phase 2: scan across chunk aggregates (in place) -----------
// One thread per channel (b,d), coalesced across d. Software-pipelined in
// groups of U=8: all of a group's loads land in registers before its stores,
// so in-place overwrite of Xagg with the EXCLUSIVE prefix is safe and the
// serial chain is C/U batched L2 round-trips instead of C.
template <int C>
__global__ __launch_bounds__(256) void phase2_k(float* Xagg,
                                                const float* __restrict__ Aagg) {
    const int g = blockIdx.x * 256 + threadIdx.x;   // 0..B*D-1
    const int b = g >> 10;                          // / D
    const int d = g & (D - 1);
    const size_t base = (size_t)b * C * D + d;
    constexpr int U = 8;
    float xb[U], ab[U];
    float h = 0.f;
    for (int c0 = 0; c0 < C; c0 += U) {
        #pragma unroll
        for (int j = 0; j < U; ++j) {
            xb[j] = Xagg[base + (size_t)(c0 + j) * D];
            ab[j] = Aagg[base + (size_t)(c0 + j) * D];
        }
        #pragma unroll
        for (int j = 0; j < U; ++j) {
            Xagg[base + (size_t)(c0 + j) * D] = h;  // h entering chunk c0+j
            h = fmaf(ab[j], h, xb[j]);
        }
    }
}

// ---------------- Phase 3: re-scan chunks seeded with incoming prefix --------
template <int C>
__global__ __launch_bounds__(256) void phase3_k(const float4* __restrict__ x,
                                                const float4* __restrict__ a,
                                                const float4* __restrict__ prefix,
                                                float4* __restrict__ out) {
    constexpr int L = S / C;
    const int t = threadIdx.x;
    const int c = blockIdx.x;
    const int b = blockIdx.y;

    float4 h = prefix[((size_t)(b * C + c)) * D4 + t];
    size_t base = ((size_t)(b * S + c * L)) * D4 + t;
    #pragma unroll 4
    for (int s = 0; s < L; ++s) {
        float4 xv = x[base + (size_t)s * D4];
        float4 av = a[base + (size_t)s * D4];
        h.x = fmaf(av.x, h.x, xv.x);
        h.y = fmaf(av.y, h.y, xv.y);
        h.z = fmaf(av.z, h.z, xv.z);
        h.w = fmaf(av.w, h.w, xv.w);
        out[base + (size_t)s * D4] = h;
    }
}

template <int C>
static void run_pipeline(const float4* x, const float4* a, float4* out,
                         void* d_ws, hipStream_t stream) {
    float* Xagg = (float*)d_ws;
    float* Aagg = Xagg + (size_t)B * C * D;
    dim3 grid1(C, B);
    phase1_k<C><<<grid1, 256, 0, stream>>>(x, a, (float4*)Xagg, (float4*)Aagg);
    phase2_k<C><<<(B * D) / 256, 256, 0, stream>>>(Xagg, Aagg);
    phase3_k<C><<<grid1, 256, 0, stream>>>(x, a, (const float4*)Xagg, out);
}

extern "C" void kernel_launch(void* const* d_in, const int* in_sizes, int n_in,
                              void* d_out, int out_size, void* d_ws, size_t ws_size,
                              hipStream_t stream) {
    const float4* x = (const float4*)d_in[0];
    const float4* a = (const float4*)d_in[1];
    float4* out = (float4*)d_out;

    // C=512 needs 2 * B*C*D * 4 B = 16.8 MiB of workspace; fall back if short.
    if (ws_size >= 2ull * B * 512 * D * sizeof(float)) {
        run_pipeline<512>(x, a, out, d_ws, stream);
    } else {
        run_pipeline<128>(x, a, out, d_ws, stream);
    }
}